// Round 5
// baseline (1612.026 us; speedup 1.0000x reference)
//
#include <hip/hip_runtime.h>

#define WN 32          // WIDTH
#define HID 8          // WIDTH/4
#define DEPTH 4

typedef float fvec4 __attribute__((ext_vector_type(4)));  // native vector for nontemporal builtins

__global__ void zero_kernel(int* __restrict__ cnt, int* __restrict__ cursor, int n) {
    int i = blockIdx.x * blockDim.x + threadIdx.x;
    if (i < n) { cnt[i] = 0; cursor[i] = 0; }
}

__global__ void count_kernel(const int* __restrict__ eidx, int* __restrict__ cnt, int e_cnt) {
    int e = blockIdx.x * blockDim.x + threadIdx.x;
    if (e >= e_cnt) return;
    atomicAdd(&cnt[eidx[e_cnt + e]], 1);
}

// Single-block exclusive scan over cnt -> row_ptr[n+1]; also inv = 1/max(cnt,1).
__global__ void scan_kernel(const int* __restrict__ cnt, int* __restrict__ row_ptr,
                            float* __restrict__ inv, int n) {
    __shared__ int s_wave[16];
    int t = threadIdx.x;
    int lane = t & 63;
    int wv = t >> 6;                 // 16 waves of 64
    int offset = 0;
    for (int base = 0; base < n; base += 1024) {
        int i = base + t;
        int v = (i < n) ? cnt[i] : 0;
        int x = v;
#pragma unroll
        for (int d = 1; d < 64; d <<= 1) {
            int y = __shfl_up(x, d, 64);
            if (lane >= d) x += y;
        }
        if (lane == 63) s_wave[wv] = x;
        __syncthreads();
        if (wv == 0 && lane < 16) {
            int y = s_wave[lane];
#pragma unroll
            for (int d = 1; d < 16; d <<= 1) {
                int z = __shfl_up(y, d, 64);
                if (lane >= d) y += z;
            }
            s_wave[lane] = y;        // inclusive over wave sums
        }
        __syncthreads();
        int waveoff = (wv > 0) ? s_wave[wv - 1] : 0;
        int total = s_wave[15];
        int incl = x + waveoff + offset;
        if (i < n) {
            row_ptr[i + 1] = incl;
            inv[i] = 1.0f / (float)(v > 1 ? v : 1);
        }
        offset += total;
        __syncthreads();
    }
    if (t == 0) row_ptr[0] = 0;
}

// Permute edges into dst-CSR order as ONE packed 16B record per edge:
// rec[pos] = {src_bits, ea0, ea1, ea2}. Single random 16B write -> one dirty
// 64B line per edge (was two lines across perm_src + perm_ea).
__global__ void scatter_kernel(const int* __restrict__ eidx, const float* __restrict__ ea,
                               const int* __restrict__ row_ptr, int* __restrict__ cursor,
                               fvec4* __restrict__ rec, int e_cnt) {
    int e = blockIdx.x * blockDim.x + threadIdx.x;
    if (e >= e_cnt) return;
    int src = eidx[e];
    int dst = eidx[e_cnt + e];
    int pos = row_ptr[dst] + atomicAdd(&cursor[dst], 1);
    fvec4 r;
    r.x = __int_as_float(src);
    r.y = ea[3 * e];
    r.z = ea[3 * e + 1];
    r.w = ea[3 * e + 2];
    rec[pos] = r;
}

// Once per call: stream packed recs, extract perm_src, compute all 3
// layer-invariant hid slices: hid_c[e] = relu(kw1_c @ ea_e + kb1_c).
__global__ void hid_all_kernel(const fvec4* __restrict__ rec,
                               const float* __restrict__ kw1, const float* __restrict__ kb1,
                               int* __restrict__ perm_src, float* __restrict__ hid_buf,
                               int e_cnt) {
    int e = blockIdx.x * blockDim.x + threadIdx.x;
    if (e >= e_cnt) return;
    fvec4 r = rec[e];
    perm_src[e] = __float_as_int(r.x);
    float a0 = r.y, a1 = r.z, a2 = r.w;
#pragma unroll
    for (int c = 0; c < 3; c++) {
        const float* w1 = kw1 + (size_t)c * HID * 3;   // uniform -> scalar loads
        const float* b1 = kb1 + (size_t)c * HID;
        float v[HID];
#pragma unroll
        for (int j = 0; j < HID; j++) {
            float u = b1[j] + w1[j * 3] * a0 + w1[j * 3 + 1] * a1 + w1[j * 3 + 2] * a2;
            v[j] = u > 0.0f ? u : 0.0f;
        }
        fvec4 lo, hi;
        lo.x = v[0]; lo.y = v[1]; lo.z = v[2]; lo.w = v[3];
        hi.x = v[4]; hi.y = v[5]; hi.z = v[6]; hi.w = v[7];
        fvec4* d4 = (fvec4*)(hid_buf + ((size_t)c * e_cnt + e) * HID);
        d4[0] = lo;
        d4[1] = hi;
    }
}

__global__ void h0_kernel(const float* __restrict__ x, const float* __restrict__ fc1_w,
                          const float* __restrict__ fc1_b, float* __restrict__ h, int n) {
    __shared__ float s_w[WN * 3];
    __shared__ float s_b[WN];
    int t = threadIdx.x;
    if (t < WN * 3) s_w[t] = fc1_w[t];
    if (t < WN) s_b[t] = fc1_b[t];
    __syncthreads();
    int i = blockIdx.x * blockDim.x + t;
    if (i >= n) return;
    float x0 = x[3 * i], x1 = x[3 * i + 1], x2 = x[3 * i + 2];
#pragma unroll
    for (int j = 0; j < WN; j++) {
        h[(size_t)i * WN + j] = s_b[j] + s_w[j * 3] * x0 + s_w[j * 3 + 1] * x1 + s_w[j * 3 + 2] * x2;
    }
}

// Fast path gather. One thread per (node, channel). Streaming reads
// (perm_src, hid) are non-temporal (nt flag) so the 4MB/XCD L2 keeps the h
// table resident for the random h[src] gather. Fused epilogue: mean + h@root
// + bias + relu.
__global__ void gather_hid_kernel(const int* __restrict__ row_ptr, const int* __restrict__ perm_src,
                                  const float* __restrict__ hid_c,
                                  const float* __restrict__ h_in, float* __restrict__ h_out,
                                  const float* __restrict__ inv,
                                  const float* __restrict__ kw2, const float* __restrict__ kb2,
                                  const float* __restrict__ root, const float* __restrict__ cbias,
                                  int n) {
    __shared__ float s_root[WN * WN];
    __shared__ float s_h[8][WN];
    int t = threadIdx.x;
    for (int i = t; i < WN * WN; i += 256) s_root[i] = root[i];

    int grp = t >> 5;
    int ch = t & 31;
    int node = blockIdx.x * 8 + grp;
    bool valid = node < n;

    const fvec4* kw2v = (const fvec4*)(kw2 + ch * HID);
    fvec4 w2lo = kw2v[0], w2hi = kw2v[1];
    float b2 = kb2[ch];
    float cb = cbias[ch];

    float hval = valid ? h_in[(size_t)node * WN + ch] : 0.0f;
    s_h[grp][ch] = hval;
    __syncthreads();

    float acc = 0.0f;
    if (valid) {
        int e0 = row_ptr[node], e1 = row_ptr[node + 1];
        const fvec4* hid4 = (const fvec4*)hid_c;
#pragma unroll 8
        for (int e = e0; e < e1; e++) {
            int src = __builtin_nontemporal_load(&perm_src[e]);
            fvec4 u = __builtin_nontemporal_load(&hid4[2 * (size_t)e]);
            fvec4 v = __builtin_nontemporal_load(&hid4[2 * (size_t)e + 1]);
            float w = b2 + w2lo.x * u.x + w2lo.y * u.y + w2lo.z * u.z + w2lo.w * u.w
                         + w2hi.x * v.x + w2hi.y * v.y + w2hi.z * v.z + w2hi.w * v.w;
            acc += h_in[(size_t)src * WN + ch] * w;
        }
    }
    if (!valid) return;

    float r = acc * inv[node] + cb;
    const float* srow = s_h[grp];
#pragma unroll
    for (int k = 0; k < WN; k++) r += srow[k] * s_root[k * WN + ch];
    h_out[(size_t)node * WN + ch] = r > 0.0f ? r : 0.0f;
}

// Fallback (small ws): inline hid recompute from packed recs.
__global__ void gather_kernel(const int* __restrict__ row_ptr, const fvec4* __restrict__ rec,
                              const float* __restrict__ h_in, float* __restrict__ h_out,
                              const float* __restrict__ inv,
                              const float* __restrict__ kw1, const float* __restrict__ kb1,
                              const float* __restrict__ kw2, const float* __restrict__ kb2,
                              const float* __restrict__ root, const float* __restrict__ cbias,
                              int n) {
    __shared__ float s_kw1[HID * 3];
    __shared__ float s_kb1[HID];
    __shared__ float s_kw2[WN * HID];
    __shared__ float s_kb2[WN];
    __shared__ float s_cb[WN];
    __shared__ float s_root[WN * WN];
    __shared__ float s_h[8][WN];
    int t = threadIdx.x;
    for (int i = t; i < WN * WN; i += 256) s_root[i] = root[i];
    if (t < HID * 3) s_kw1[t] = kw1[t];
    if (t < HID) s_kb1[t] = kb1[t];
    if (t < WN * HID) s_kw2[t] = kw2[t];
    if (t < WN) { s_kb2[t] = kb2[t]; s_cb[t] = cbias[t]; }
    __syncthreads();

    int grp = t >> 5;
    int ch = t & 31;
    int node = blockIdx.x * 8 + grp;

    float hval = (node < n) ? h_in[(size_t)node * WN + ch] : 0.0f;
    s_h[grp][ch] = hval;
    __syncthreads();
    if (node >= n) return;

    float w2[HID];
#pragma unroll
    for (int j = 0; j < HID; j++) w2[j] = s_kw2[ch * HID + j];
    float b2 = s_kb2[ch];

    float acc = 0.0f;
    int e0 = row_ptr[node], e1 = row_ptr[node + 1];
    for (int e = e0; e < e1; e++) {
        fvec4 r = rec[e];
        int src = __float_as_int(r.x);
        float w = b2;
#pragma unroll
        for (int j = 0; j < HID; j++) {
            float v = s_kb1[j] + s_kw1[j * 3] * r.y + s_kw1[j * 3 + 1] * r.z + s_kw1[j * 3 + 2] * r.w;
            v = v > 0.0f ? v : 0.0f;
            w += w2[j] * v;
        }
        acc += h_in[(size_t)src * WN + ch] * w;
    }

    float rr = acc * inv[node] + s_cb[ch];
    const float* srow = s_h[grp];
#pragma unroll
    for (int k = 0; k < WN; k++) rr += srow[k] * s_root[k * WN + ch];
    h_out[(size_t)node * WN + ch] = rr > 0.0f ? rr : 0.0f;
}

__global__ void out_kernel(const float* __restrict__ h, const float* __restrict__ fc2_w,
                           const float* __restrict__ fc2_b, float* __restrict__ out, int n) {
    __shared__ float s_w[WN];
    __shared__ float s_b;
    int t = threadIdx.x;
    if (t < WN) s_w[t] = fc2_w[t];
    if (t == 0) s_b = fc2_b[0];
    __syncthreads();
    int i = blockIdx.x * blockDim.x + t;
    if (i >= n) return;
    float acc = s_b;
#pragma unroll
    for (int k = 0; k < WN; k++) acc += h[(size_t)i * WN + k] * s_w[k];
    out[i] = acc;
}

extern "C" void kernel_launch(void* const* d_in, const int* in_sizes, int n_in,
                              void* d_out, int out_size, void* d_ws, size_t ws_size,
                              hipStream_t stream) {
    const float* x      = (const float*)d_in[0];
    const int*   eidx   = (const int*)d_in[1];
    const float* ea     = (const float*)d_in[2];
    const float* fc1_w  = (const float*)d_in[3];
    const float* fc1_b  = (const float*)d_in[4];
    const float* fc2_w  = (const float*)d_in[5];
    const float* fc2_b  = (const float*)d_in[6];
    const float* kw1    = (const float*)d_in[7];
    const float* kb1    = (const float*)d_in[8];
    const float* kw2    = (const float*)d_in[9];
    const float* kb2    = (const float*)d_in[10];
    const float* root   = (const float*)d_in[11];
    const float* cbias  = (const float*)d_in[12];
    float* out = (float*)d_out;

    const int n = in_sizes[0] / 3;       // 50000
    const int e_cnt = in_sizes[2] / 3;   // 1600000

    // workspace layout (floats, 16B-aligned sections)
    auto pad4 = [](size_t v) { return (v + 3) & ~(size_t)3; };
    float* ws = (float*)d_ws;
    size_t off = 0;
    float* hA       = ws + off; off += pad4((size_t)n * WN);
    float* hB       = ws + off; off += pad4((size_t)n * WN);
    float* inv      = ws + off; off += pad4(n);
    int*   cnt      = (int*)(ws + off); off += pad4(n);
    int*   cursor   = (int*)(ws + off); off += pad4(n);
    int*   row_ptr  = (int*)(ws + off); off += pad4(n + 1);
    fvec4* rec      = (fvec4*)(ws + off); off += (size_t)4 * e_cnt;
    int*   perm_src = (int*)(ws + off); off += pad4(e_cnt);
    float* hid_buf  = ws + off; off += (size_t)3 * e_cnt * HID;
    bool full_path = (ws_size >= off * sizeof(float));

    const int B = 256;
    int grid_n  = (n + B - 1) / B;
    int grid_e  = (e_cnt + B - 1) / B;
    int grid_g  = (n + 7) / 8;

    zero_kernel<<<grid_n, B, 0, stream>>>(cnt, cursor, n);
    count_kernel<<<grid_e, B, 0, stream>>>(eidx, cnt, e_cnt);
    scan_kernel<<<1, 1024, 0, stream>>>(cnt, row_ptr, inv, n);
    scatter_kernel<<<grid_e, B, 0, stream>>>(eidx, ea, row_ptr, cursor, rec, e_cnt);
    if (full_path) {
        hid_all_kernel<<<grid_e, B, 0, stream>>>(rec, kw1, kb1, perm_src, hid_buf, e_cnt);
    }
    h0_kernel<<<grid_n, B, 0, stream>>>(x, fc1_w, fc1_b, hA, n);

    float* hin = hA;
    float* hout = hB;
    for (int d = 0; d < DEPTH; d++) {
        for (int c = 0; c < 3; c++) {
            if (full_path) {
                gather_hid_kernel<<<grid_g, B, 0, stream>>>(
                    row_ptr, perm_src, hid_buf + (size_t)c * e_cnt * HID,
                    hin, hout, inv,
                    kw2 + (size_t)c * WN * HID, kb2 + (size_t)c * WN,
                    root + (size_t)c * WN * WN, cbias + (size_t)c * WN, n);
            } else {
                gather_kernel<<<grid_g, B, 0, stream>>>(
                    row_ptr, rec, hin, hout, inv,
                    kw1 + (size_t)c * HID * 3, kb1 + (size_t)c * HID,
                    kw2 + (size_t)c * WN * HID, kb2 + (size_t)c * WN,
                    root + (size_t)c * WN * WN, cbias + (size_t)c * WN, n);
            }
            float* tmp = hin; hin = hout; hout = tmp;
        }
    }
    // 12 swaps -> final h is in hin
    out_kernel<<<grid_n, B, 0, stream>>>(hin, fc2_w, fc2_b, out, n);
}

// Round 6
// 874.775 us; speedup vs baseline: 1.8428x; 1.8428x over previous
//
#include <hip/hip_runtime.h>

#define WN 32          // WIDTH
#define HID 8          // WIDTH/4
#define DEPTH 4

typedef float fvec4 __attribute__((ext_vector_type(4)));

__global__ void zero_kernel(int* __restrict__ cnt, int* __restrict__ cursor, int n) {
    int i = blockIdx.x * blockDim.x + threadIdx.x;
    if (i < n) { cnt[i] = 0; cursor[i] = 0; }
}

__global__ void count_kernel(const int* __restrict__ eidx, int* __restrict__ cnt, int e_cnt) {
    int e = blockIdx.x * blockDim.x + threadIdx.x;
    if (e >= e_cnt) return;
    atomicAdd(&cnt[eidx[e_cnt + e]], 1);
}

// Single-block exclusive scan over cnt -> row_ptr[n+1]; also inv = 1/max(cnt,1).
__global__ void scan_kernel(const int* __restrict__ cnt, int* __restrict__ row_ptr,
                            float* __restrict__ inv, int n) {
    __shared__ int s_wave[16];
    int t = threadIdx.x;
    int lane = t & 63;
    int wv = t >> 6;                 // 16 waves of 64
    int offset = 0;
    for (int base = 0; base < n; base += 1024) {
        int i = base + t;
        int v = (i < n) ? cnt[i] : 0;
        int x = v;
#pragma unroll
        for (int d = 1; d < 64; d <<= 1) {
            int y = __shfl_up(x, d, 64);
            if (lane >= d) x += y;
        }
        if (lane == 63) s_wave[wv] = x;
        __syncthreads();
        if (wv == 0 && lane < 16) {
            int y = s_wave[lane];
#pragma unroll
            for (int d = 1; d < 16; d <<= 1) {
                int z = __shfl_up(y, d, 64);
                if (lane >= d) y += z;
            }
            s_wave[lane] = y;        // inclusive over wave sums
        }
        __syncthreads();
        int waveoff = (wv > 0) ? s_wave[wv - 1] : 0;
        int total = s_wave[15];
        int incl = x + waveoff + offset;
        if (i < n) {
            row_ptr[i + 1] = incl;
            inv[i] = 1.0f / (float)(v > 1 ? v : 1);
        }
        offset += total;
        __syncthreads();
    }
    if (t == 0) row_ptr[0] = 0;
}

// Permute edges into dst-CSR order as ONE packed 16B record per edge:
// rec[pos] = {src_bits, ea0, ea1, ea2} -> single dirty 64B line per edge.
__global__ void scatter_kernel(const int* __restrict__ eidx, const float* __restrict__ ea,
                               const int* __restrict__ row_ptr, int* __restrict__ cursor,
                               fvec4* __restrict__ rec, int e_cnt) {
    int e = blockIdx.x * blockDim.x + threadIdx.x;
    if (e >= e_cnt) return;
    int src = eidx[e];
    int dst = eidx[e_cnt + e];
    int pos = row_ptr[dst] + atomicAdd(&cursor[dst], 1);
    fvec4 r;
    r.x = __int_as_float(src);
    r.y = ea[3 * e];
    r.z = ea[3 * e + 1];
    r.w = ea[3 * e + 2];
    rec[pos] = r;
}

// Once per call: stream packed recs, extract perm_src, compute all 3
// layer-invariant hid slices: hid_c[e] = relu(kw1_c @ ea_e + kb1_c).
__global__ void hid_all_kernel(const fvec4* __restrict__ rec,
                               const float* __restrict__ kw1, const float* __restrict__ kb1,
                               int* __restrict__ perm_src, float* __restrict__ hid_buf,
                               int e_cnt) {
    int e = blockIdx.x * blockDim.x + threadIdx.x;
    if (e >= e_cnt) return;
    fvec4 r = rec[e];
    perm_src[e] = __float_as_int(r.x);
    float a0 = r.y, a1 = r.z, a2 = r.w;
#pragma unroll
    for (int c = 0; c < 3; c++) {
        const float* w1 = kw1 + (size_t)c * HID * 3;   // uniform -> scalar loads
        const float* b1 = kb1 + (size_t)c * HID;
        float v[HID];
#pragma unroll
        for (int j = 0; j < HID; j++) {
            float u = b1[j] + w1[j * 3] * a0 + w1[j * 3 + 1] * a1 + w1[j * 3 + 2] * a2;
            v[j] = u > 0.0f ? u : 0.0f;
        }
        fvec4 lo, hi;
        lo.x = v[0]; lo.y = v[1]; lo.z = v[2]; lo.w = v[3];
        hi.x = v[4]; hi.y = v[5]; hi.z = v[6]; hi.w = v[7];
        fvec4* d4 = (fvec4*)(hid_buf + ((size_t)c * e_cnt + e) * HID);
        d4[0] = lo;
        d4[1] = hi;
    }
}

__global__ void h0_kernel(const float* __restrict__ x, const float* __restrict__ fc1_w,
                          const float* __restrict__ fc1_b, float* __restrict__ h, int n) {
    __shared__ float s_w[WN * 3];
    __shared__ float s_b[WN];
    int t = threadIdx.x;
    if (t < WN * 3) s_w[t] = fc1_w[t];
    if (t < WN) s_b[t] = fc1_b[t];
    __syncthreads();
    int i = blockIdx.x * blockDim.x + t;
    if (i >= n) return;
    float x0 = x[3 * i], x1 = x[3 * i + 1], x2 = x[3 * i + 2];
#pragma unroll
    for (int j = 0; j < WN; j++) {
        h[(size_t)i * WN + j] = s_b[j] + s_w[j * 3] * x0 + s_w[j * 3 + 1] * x1 + s_w[j * 3 + 2] * x2;
    }
}

// Cooperative gather. 8 node-groups x 32 channel-threads per block.
// Per 32-edge chunk: the group's 32 threads cooperatively stage src + hid
// records into LDS (coalesced), then each thread loops the chunk with
// latency-free LDS src/hid (broadcast reads) and independent coalesced
// 128B h-row gathers. Fused epilogue: mean + h@root + bias + relu.
__global__ void gather_hid_kernel(const int* __restrict__ row_ptr, const int* __restrict__ perm_src,
                                  const float* __restrict__ hid_c,
                                  const float* __restrict__ h_in, float* __restrict__ h_out,
                                  const float* __restrict__ inv,
                                  const float* __restrict__ kw2, const float* __restrict__ kb2,
                                  const float* __restrict__ root, const float* __restrict__ cbias,
                                  int n) {
    __shared__ float s_root[WN * WN];
    __shared__ float s_h[8][WN];
    __shared__ int   s_src[8][32];
    __shared__ float s_hid[8][32][HID];
    __shared__ int   s_maxdeg;
    int t = threadIdx.x;
    if (t == 0) s_maxdeg = 0;
    for (int i = t; i < WN * WN; i += 256) s_root[i] = root[i];

    int grp = t >> 5;
    int ch = t & 31;
    int node = blockIdx.x * 8 + grp;
    bool valid = node < n;

    const fvec4* kw2v = (const fvec4*)(kw2 + ch * HID);
    fvec4 w2lo = kw2v[0], w2hi = kw2v[1];
    float b2 = kb2[ch];
    float cb = cbias[ch];

    float hval = valid ? h_in[(size_t)node * WN + ch] : 0.0f;
    s_h[grp][ch] = hval;

    int e0 = 0, e1 = 0;
    if (valid) { e0 = row_ptr[node]; e1 = row_ptr[node + 1]; }
    int deg = e1 - e0;
    __syncthreads();
    if (valid && ch == 0 && deg > 0) atomicMax(&s_maxdeg, deg);
    __syncthreads();
    int nchunk = (s_maxdeg + 31) >> 5;   // block-uniform

    const fvec4* hid4 = (const fvec4*)hid_c;
    float acc = 0.0f;
    for (int cs = 0; cs < nchunk; cs++) {
        int ebase = e0 + (cs << 5);
        int e = ebase + ch;
        if (e < e1) {
            s_src[grp][ch] = perm_src[e];
            const fvec4* hp = hid4 + 2 * (size_t)e;
            fvec4 u = hp[0];
            fvec4 v = hp[1];
            fvec4* dp = (fvec4*)&s_hid[grp][ch][0];
            dp[0] = u;
            dp[1] = v;
        }
        __syncthreads();
        int rem = e1 - ebase;
        int cnt = rem < 32 ? rem : 32;   // <=0 for finished/invalid groups
#pragma unroll 4
        for (int i = 0; i < cnt; i++) {
            int src = s_src[grp][i];
            const float* hd = s_hid[grp][i];
            float w = b2 + w2lo.x * hd[0] + w2lo.y * hd[1] + w2lo.z * hd[2] + w2lo.w * hd[3]
                         + w2hi.x * hd[4] + w2hi.y * hd[5] + w2hi.z * hd[6] + w2hi.w * hd[7];
            acc += h_in[(size_t)src * WN + ch] * w;
        }
        __syncthreads();
    }
    if (!valid) return;

    float r = acc * inv[node] + cb;
    const float* srow = s_h[grp];
#pragma unroll
    for (int k = 0; k < WN; k++) r += srow[k] * s_root[k * WN + ch];
    h_out[(size_t)node * WN + ch] = r > 0.0f ? r : 0.0f;
}

// Fallback (small ws): inline hid recompute from packed recs.
__global__ void gather_kernel(const int* __restrict__ row_ptr, const fvec4* __restrict__ rec,
                              const float* __restrict__ h_in, float* __restrict__ h_out,
                              const float* __restrict__ inv,
                              const float* __restrict__ kw1, const float* __restrict__ kb1,
                              const float* __restrict__ kw2, const float* __restrict__ kb2,
                              const float* __restrict__ root, const float* __restrict__ cbias,
                              int n) {
    __shared__ float s_kw1[HID * 3];
    __shared__ float s_kb1[HID];
    __shared__ float s_kw2[WN * HID];
    __shared__ float s_kb2[WN];
    __shared__ float s_cb[WN];
    __shared__ float s_root[WN * WN];
    __shared__ float s_h[8][WN];
    int t = threadIdx.x;
    for (int i = t; i < WN * WN; i += 256) s_root[i] = root[i];
    if (t < HID * 3) s_kw1[t] = kw1[t];
    if (t < HID) s_kb1[t] = kb1[t];
    if (t < WN * HID) s_kw2[t] = kw2[t];
    if (t < WN) { s_kb2[t] = kb2[t]; s_cb[t] = cbias[t]; }
    __syncthreads();

    int grp = t >> 5;
    int ch = t & 31;
    int node = blockIdx.x * 8 + grp;

    float hval = (node < n) ? h_in[(size_t)node * WN + ch] : 0.0f;
    s_h[grp][ch] = hval;
    __syncthreads();
    if (node >= n) return;

    float w2[HID];
#pragma unroll
    for (int j = 0; j < HID; j++) w2[j] = s_kw2[ch * HID + j];
    float b2 = s_kb2[ch];

    float acc = 0.0f;
    int e0 = row_ptr[node], e1 = row_ptr[node + 1];
    for (int e = e0; e < e1; e++) {
        fvec4 r = rec[e];
        int src = __float_as_int(r.x);
        float w = b2;
#pragma unroll
        for (int j = 0; j < HID; j++) {
            float v = s_kb1[j] + s_kw1[j * 3] * r.y + s_kw1[j * 3 + 1] * r.z + s_kw1[j * 3 + 2] * r.w;
            v = v > 0.0f ? v : 0.0f;
            w += w2[j] * v;
        }
        acc += h_in[(size_t)src * WN + ch] * w;
    }

    float rr = acc * inv[node] + s_cb[ch];
    const float* srow = s_h[grp];
#pragma unroll
    for (int k = 0; k < WN; k++) rr += srow[k] * s_root[k * WN + ch];
    h_out[(size_t)node * WN + ch] = rr > 0.0f ? rr : 0.0f;
}

__global__ void out_kernel(const float* __restrict__ h, const float* __restrict__ fc2_w,
                           const float* __restrict__ fc2_b, float* __restrict__ out, int n) {
    __shared__ float s_w[WN];
    __shared__ float s_b;
    int t = threadIdx.x;
    if (t < WN) s_w[t] = fc2_w[t];
    if (t == 0) s_b = fc2_b[0];
    __syncthreads();
    int i = blockIdx.x * blockDim.x + t;
    if (i >= n) return;
    float acc = s_b;
#pragma unroll
    for (int k = 0; k < WN; k++) acc += h[(size_t)i * WN + k] * s_w[k];
    out[i] = acc;
}

extern "C" void kernel_launch(void* const* d_in, const int* in_sizes, int n_in,
                              void* d_out, int out_size, void* d_ws, size_t ws_size,
                              hipStream_t stream) {
    const float* x      = (const float*)d_in[0];
    const int*   eidx   = (const int*)d_in[1];
    const float* ea     = (const float*)d_in[2];
    const float* fc1_w  = (const float*)d_in[3];
    const float* fc1_b  = (const float*)d_in[4];
    const float* fc2_w  = (const float*)d_in[5];
    const float* fc2_b  = (const float*)d_in[6];
    const float* kw1    = (const float*)d_in[7];
    const float* kb1    = (const float*)d_in[8];
    const float* kw2    = (const float*)d_in[9];
    const float* kb2    = (const float*)d_in[10];
    const float* root   = (const float*)d_in[11];
    const float* cbias  = (const float*)d_in[12];
    float* out = (float*)d_out;

    const int n = in_sizes[0] / 3;       // 50000
    const int e_cnt = in_sizes[2] / 3;   // 1600000

    // workspace layout (floats, 16B-aligned sections)
    auto pad4 = [](size_t v) { return (v + 3) & ~(size_t)3; };
    float* ws = (float*)d_ws;
    size_t off = 0;
    float* hA       = ws + off; off += pad4((size_t)n * WN);
    float* hB       = ws + off; off += pad4((size_t)n * WN);
    float* inv      = ws + off; off += pad4(n);
    int*   cnt      = (int*)(ws + off); off += pad4(n);
    int*   cursor   = (int*)(ws + off); off += pad4(n);
    int*   row_ptr  = (int*)(ws + off); off += pad4(n + 1);
    fvec4* rec      = (fvec4*)(ws + off); off += (size_t)4 * e_cnt;
    int*   perm_src = (int*)(ws + off); off += pad4(e_cnt);
    float* hid_buf  = ws + off; off += (size_t)3 * e_cnt * HID;
    bool full_path = (ws_size >= off * sizeof(float));

    const int B = 256;
    int grid_n  = (n + B - 1) / B;
    int grid_e  = (e_cnt + B - 1) / B;
    int grid_g  = (n + 7) / 8;

    zero_kernel<<<grid_n, B, 0, stream>>>(cnt, cursor, n);
    count_kernel<<<grid_e, B, 0, stream>>>(eidx, cnt, e_cnt);
    scan_kernel<<<1, 1024, 0, stream>>>(cnt, row_ptr, inv, n);
    scatter_kernel<<<grid_e, B, 0, stream>>>(eidx, ea, row_ptr, cursor, rec, e_cnt);
    if (full_path) {
        hid_all_kernel<<<grid_e, B, 0, stream>>>(rec, kw1, kb1, perm_src, hid_buf, e_cnt);
    }
    h0_kernel<<<grid_n, B, 0, stream>>>(x, fc1_w, fc1_b, hA, n);

    float* hin = hA;
    float* hout = hB;
    for (int d = 0; d < DEPTH; d++) {
        for (int c = 0; c < 3; c++) {
            if (full_path) {
                gather_hid_kernel<<<grid_g, B, 0, stream>>>(
                    row_ptr, perm_src, hid_buf + (size_t)c * e_cnt * HID,
                    hin, hout, inv,
                    kw2 + (size_t)c * WN * HID, kb2 + (size_t)c * WN,
                    root + (size_t)c * WN * WN, cbias + (size_t)c * WN, n);
            } else {
                gather_kernel<<<grid_g, B, 0, stream>>>(
                    row_ptr, rec, hin, hout, inv,
                    kw1 + (size_t)c * HID * 3, kb1 + (size_t)c * HID,
                    kw2 + (size_t)c * WN * HID, kb2 + (size_t)c * WN,
                    root + (size_t)c * WN * WN, cbias + (size_t)c * WN, n);
            }
            float* tmp = hin; hin = hout; hout = tmp;
        }
    }
    // 12 swaps -> final h is in hin
    out_kernel<<<grid_n, B, 0, stream>>>(hin, fc2_w, fc2_b, out, n);
}

// Round 7
// 764.030 us; speedup vs baseline: 2.1099x; 1.1449x over previous
//
#include <hip/hip_runtime.h>

#define WN 32          // WIDTH
#define HID 8          // WIDTH/4
#define DEPTH 4
#define GPB 16         // node-groups per block (16 threads x 2 channels each)

typedef float fvec4 __attribute__((ext_vector_type(4)));

__global__ void zero_kernel(int* __restrict__ cnt, int* __restrict__ cursor, int n) {
    int i = blockIdx.x * blockDim.x + threadIdx.x;
    if (i < n) { cnt[i] = 0; cursor[i] = 0; }
}

__global__ void count_kernel(const int* __restrict__ eidx, int* __restrict__ cnt, int e_cnt) {
    int e = blockIdx.x * blockDim.x + threadIdx.x;
    if (e >= e_cnt) return;
    atomicAdd(&cnt[eidx[e_cnt + e]], 1);
}

// Single-block exclusive scan over cnt -> row_ptr[n+1]; also inv = 1/max(cnt,1).
__global__ void scan_kernel(const int* __restrict__ cnt, int* __restrict__ row_ptr,
                            float* __restrict__ inv, int n) {
    __shared__ int s_wave[16];
    int t = threadIdx.x;
    int lane = t & 63;
    int wv = t >> 6;                 // 16 waves of 64
    int offset = 0;
    for (int base = 0; base < n; base += 1024) {
        int i = base + t;
        int v = (i < n) ? cnt[i] : 0;
        int x = v;
#pragma unroll
        for (int d = 1; d < 64; d <<= 1) {
            int y = __shfl_up(x, d, 64);
            if (lane >= d) x += y;
        }
        if (lane == 63) s_wave[wv] = x;
        __syncthreads();
        if (wv == 0 && lane < 16) {
            int y = s_wave[lane];
#pragma unroll
            for (int d = 1; d < 16; d <<= 1) {
                int z = __shfl_up(y, d, 64);
                if (lane >= d) y += z;
            }
            s_wave[lane] = y;        // inclusive over wave sums
        }
        __syncthreads();
        int waveoff = (wv > 0) ? s_wave[wv - 1] : 0;
        int total = s_wave[15];
        int incl = x + waveoff + offset;
        if (i < n) {
            row_ptr[i + 1] = incl;
            inv[i] = 1.0f / (float)(v > 1 ? v : 1);
        }
        offset += total;
        __syncthreads();
    }
    if (t == 0) row_ptr[0] = 0;
}

// Permute edges into dst-CSR order as ONE packed 16B record per edge:
// rec[pos] = {src_bits, ea0, ea1, ea2} -> single dirty 64B line per edge.
__global__ void scatter_kernel(const int* __restrict__ eidx, const float* __restrict__ ea,
                               const int* __restrict__ row_ptr, int* __restrict__ cursor,
                               fvec4* __restrict__ rec, int e_cnt) {
    int e = blockIdx.x * blockDim.x + threadIdx.x;
    if (e >= e_cnt) return;
    int src = eidx[e];
    int dst = eidx[e_cnt + e];
    int pos = row_ptr[dst] + atomicAdd(&cursor[dst], 1);
    fvec4 r;
    r.x = __int_as_float(src);
    r.y = ea[3 * e];
    r.z = ea[3 * e + 1];
    r.w = ea[3 * e + 2];
    rec[pos] = r;
}

__global__ void h0_kernel(const float* __restrict__ x, const float* __restrict__ fc1_w,
                          const float* __restrict__ fc1_b, float* __restrict__ h, int n) {
    __shared__ float s_w[WN * 3];
    __shared__ float s_b[WN];
    int t = threadIdx.x;
    if (t < WN * 3) s_w[t] = fc1_w[t];
    if (t < WN) s_b[t] = fc1_b[t];
    __syncthreads();
    int i = blockIdx.x * blockDim.x + t;
    if (i >= n) return;
    float x0 = x[3 * i], x1 = x[3 * i + 1], x2 = x[3 * i + 2];
#pragma unroll
    for (int j = 0; j < WN; j++) {
        h[(size_t)i * WN + j] = s_b[j] + s_w[j * 3] * x0 + s_w[j * 3 + 1] * x1 + s_w[j * 3 + 2] * x2;
    }
}

// Cooperative gather, 2-channel register blocking. 16 node-groups x 16
// threads; thread owns channels (2tc, 2tc+1). Per 32-edge chunk: threads
// stage 2 recs each (coalesced 16B loads), recompute hid in-register
// (kw1/kb1 scalarize to SGPRs), write conflict-free split u/v LDS arrays.
// Inner loop: LDS broadcast src/hid + independent coalesced float2 h-gather,
// 2 channels per hid read. Fused epilogue: mean + h@root + bias + relu.
__global__ void gather2_kernel(const int* __restrict__ row_ptr, const fvec4* __restrict__ rec,
                               const float* __restrict__ h_in, float* __restrict__ h_out,
                               const float* __restrict__ inv,
                               const float* __restrict__ kw1, const float* __restrict__ kb1,
                               const float* __restrict__ kw2, const float* __restrict__ kb2,
                               const float* __restrict__ root, const float* __restrict__ cbias,
                               int n) {
    __shared__ float s_root[WN * 34];        // row stride 34: float2-aligned, conflict-free
    __shared__ float s_h[GPB * 34];          // group stride 34
    __shared__ int   s_src[GPB][33];         // group stride 33 -> distinct banks per group
    __shared__ fvec4 s_hid_u[GPB][33];       // 16B lane stride writes: conflict-free
    __shared__ fvec4 s_hid_v[GPB][33];
    __shared__ int   s_maxdeg;

    int t = threadIdx.x;
    if (t == 0) s_maxdeg = 0;
    for (int i = t; i < WN * WN; i += 256) s_root[(i >> 5) * 34 + (i & 31)] = root[i];

    int grp = t >> 4;          // 0..15
    int tc  = t & 15;          // 0..15, channels 2tc, 2tc+1
    int node = blockIdx.x * GPB + grp;
    bool valid = node < n;

    // per-thread weight columns for 2 output channels (16 floats, coalesced)
    const fvec4* kwp = (const fvec4*)(kw2 + tc * 16);
    fvec4 wa0 = kwp[0], wa1 = kwp[1];        // channel 2tc
    fvec4 wb0 = kwp[2], wb1 = kwp[3];        // channel 2tc+1
    float2 b2 = *(const float2*)(kb2 + 2 * tc);
    float2 cb = *(const float2*)(cbias + 2 * tc);

    int e0 = 0, e1 = 0;
    float2 hself = {0.0f, 0.0f};
    if (valid) {
        e0 = row_ptr[node];
        e1 = row_ptr[node + 1];
        hself = *(const float2*)(h_in + (size_t)node * WN + 2 * tc);
    }
    *(float2*)&s_h[grp * 34 + 2 * tc] = hself;
    int deg = e1 - e0;
    __syncthreads();                         // s_maxdeg init + s_root/s_h visible
    if (valid && tc == 0 && deg > 0) atomicMax(&s_maxdeg, deg);
    __syncthreads();
    int nchunk = (s_maxdeg + 31) >> 5;       // block-uniform

    float acc0 = 0.0f, acc1 = 0.0f;
    for (int cs = 0; cs < nchunk; cs++) {
        int ebase = e0 + (cs << 5);
        // stage 32 edges: 2 per thread, hid recomputed in-register
#pragma unroll
        for (int s = 0; s < 2; s++) {
            int li = tc + (s << 4);
            int e = ebase + li;
            if (e < e1) {
                fvec4 r = rec[e];
                s_src[grp][li] = __float_as_int(r.x);
                float hv[HID];
#pragma unroll
                for (int j = 0; j < HID; j++) {
                    float u = kb1[j] + kw1[3 * j] * r.y + kw1[3 * j + 1] * r.z + kw1[3 * j + 2] * r.w;
                    hv[j] = u > 0.0f ? u : 0.0f;
                }
                fvec4 lo, hi;
                lo.x = hv[0]; lo.y = hv[1]; lo.z = hv[2]; lo.w = hv[3];
                hi.x = hv[4]; hi.y = hv[5]; hi.z = hv[6]; hi.w = hv[7];
                s_hid_u[grp][li] = lo;
                s_hid_v[grp][li] = hi;
            }
        }
        __syncthreads();
        int rem = e1 - ebase;
        int cnt = rem < 32 ? rem : 32;       // <=0 for finished/invalid groups
#pragma unroll 4
        for (int i = 0; i < cnt; i++) {
            int src = s_src[grp][i];
            fvec4 u = s_hid_u[grp][i];
            fvec4 v = s_hid_v[grp][i];
            float w0 = b2.x + wa0.x * u.x + wa0.y * u.y + wa0.z * u.z + wa0.w * u.w
                            + wa1.x * v.x + wa1.y * v.y + wa1.z * v.z + wa1.w * v.w;
            float w1 = b2.y + wb0.x * u.x + wb0.y * u.y + wb0.z * u.z + wb0.w * u.w
                            + wb1.x * v.x + wb1.y * v.y + wb1.z * v.z + wb1.w * v.w;
            float2 hh = *(const float2*)(h_in + (size_t)src * WN + 2 * tc);
            acc0 += hh.x * w0;
            acc1 += hh.y * w1;
        }
        __syncthreads();
    }
    if (!valid) return;

    float invn = inv[node];
    float r0 = acc0 * invn + cb.x;
    float r1 = acc1 * invn + cb.y;
#pragma unroll
    for (int k = 0; k < WN; k++) {
        float hk = s_h[grp * 34 + k];
        float2 rt = *(const float2*)&s_root[k * 34 + 2 * tc];
        r0 += hk * rt.x;
        r1 += hk * rt.y;
    }
    float2 o;
    o.x = r0 > 0.0f ? r0 : 0.0f;
    o.y = r1 > 0.0f ? r1 : 0.0f;
    *(float2*)(h_out + (size_t)node * WN + 2 * tc) = o;
}

__global__ void out_kernel(const float* __restrict__ h, const float* __restrict__ fc2_w,
                           const float* __restrict__ fc2_b, float* __restrict__ out, int n) {
    __shared__ float s_w[WN];
    __shared__ float s_b;
    int t = threadIdx.x;
    if (t < WN) s_w[t] = fc2_w[t];
    if (t == 0) s_b = fc2_b[0];
    __syncthreads();
    int i = blockIdx.x * blockDim.x + t;
    if (i >= n) return;
    float acc = s_b;
#pragma unroll
    for (int k = 0; k < WN; k++) acc += h[(size_t)i * WN + k] * s_w[k];
    out[i] = acc;
}

extern "C" void kernel_launch(void* const* d_in, const int* in_sizes, int n_in,
                              void* d_out, int out_size, void* d_ws, size_t ws_size,
                              hipStream_t stream) {
    const float* x      = (const float*)d_in[0];
    const int*   eidx   = (const int*)d_in[1];
    const float* ea     = (const float*)d_in[2];
    const float* fc1_w  = (const float*)d_in[3];
    const float* fc1_b  = (const float*)d_in[4];
    const float* fc2_w  = (const float*)d_in[5];
    const float* fc2_b  = (const float*)d_in[6];
    const float* kw1    = (const float*)d_in[7];
    const float* kb1    = (const float*)d_in[8];
    const float* kw2    = (const float*)d_in[9];
    const float* kb2    = (const float*)d_in[10];
    const float* root   = (const float*)d_in[11];
    const float* cbias  = (const float*)d_in[12];
    float* out = (float*)d_out;

    const int n = in_sizes[0] / 3;       // 50000
    const int e_cnt = in_sizes[2] / 3;   // 1600000

    // workspace layout (floats, 16B-aligned sections)
    auto pad4 = [](size_t v) { return (v + 3) & ~(size_t)3; };
    float* ws = (float*)d_ws;
    size_t off = 0;
    float* hA       = ws + off; off += pad4((size_t)n * WN);
    float* hB       = ws + off; off += pad4((size_t)n * WN);
    float* inv      = ws + off; off += pad4(n);
    int*   cnt      = (int*)(ws + off); off += pad4(n);
    int*   cursor   = (int*)(ws + off); off += pad4(n);
    int*   row_ptr  = (int*)(ws + off); off += pad4(n + 1);
    fvec4* rec      = (fvec4*)(ws + off); off += (size_t)4 * e_cnt;

    const int B = 256;
    int grid_n  = (n + B - 1) / B;
    int grid_e  = (e_cnt + B - 1) / B;
    int grid_g  = (n + GPB - 1) / GPB;

    zero_kernel<<<grid_n, B, 0, stream>>>(cnt, cursor, n);
    count_kernel<<<grid_e, B, 0, stream>>>(eidx, cnt, e_cnt);
    scan_kernel<<<1, 1024, 0, stream>>>(cnt, row_ptr, inv, n);
    scatter_kernel<<<grid_e, B, 0, stream>>>(eidx, ea, row_ptr, cursor, rec, e_cnt);
    h0_kernel<<<grid_n, B, 0, stream>>>(x, fc1_w, fc1_b, hA, n);

    float* hin = hA;
    float* hout = hB;
    for (int d = 0; d < DEPTH; d++) {
        for (int c = 0; c < 3; c++) {
            gather2_kernel<<<grid_g, B, 0, stream>>>(
                row_ptr, rec, hin, hout, inv,
                kw1 + (size_t)c * HID * 3, kb1 + (size_t)c * HID,
                kw2 + (size_t)c * WN * HID, kb2 + (size_t)c * WN,
                root + (size_t)c * WN * WN, cbias + (size_t)c * WN, n);
            float* tmp = hin; hin = hout; hout = tmp;
        }
    }
    // 12 swaps -> final h is in hin
    out_kernel<<<grid_n, B, 0, stream>>>(hin, fc2_w, fc2_b, out, n);
}